// Round 1
// baseline (325.359 us; speedup 1.0000x reference)
//
#include <hip/hip_runtime.h>
#include <stdint.h>

#define NLEV 5
#define NIMG 32
#define NCLS 15
#define KMAX 1000

// ---------------- score kernel ----------------
// per position: sigmoid over 15 classes (f64 for exactness), max+argmax,
// candidate mask, write ordered-score key (0 if not candidate) + label.
__global__ void score_kernel(const float* __restrict__ cls,
                             const float* __restrict__ ctr,
                             uint32_t* __restrict__ sc,
                             uint8_t* __restrict__ lab,
                             int hw, int shift, int total)
{
    int g = blockIdx.x * blockDim.x + threadIdx.x;
    if (g >= total) return;
    int n = g >> shift;
    int i = g & (hw - 1);
    const float* cp = cls + (size_t)n * NCLS * hw + i;
    float best = -1.0f;
    int bl = 0;
    for (int c = 0; c < NCLS; ++c) {
        float x = cp[(size_t)c * hw];
        float p = (float)(1.0 / (1.0 + exp(-(double)x)));
        if (p > best) { best = p; bl = c; }
    }
    float cf = (float)(1.0 / (1.0 + exp(-(double)ctr[g])));
    bool cand = (best * cf) > 0.2f;
    // ordered transform for positive floats: set sign bit -> unsigned order == float order
    uint32_t o = cand ? (__float_as_uint(best) | 0x80000000u) : 0u;
    sc[g] = o;
    lab[g] = (uint8_t)bl;
}

// ---------------- select kernel ----------------
// one block per (level, image): radix-select m-th largest, compact, bitonic
// sort 1024 keys, gather + write 1000 output rows.
__global__ __launch_bounds__(256) void select_kernel(
    const uint32_t* __restrict__ sc_all,
    const uint8_t* __restrict__ lab_all,
    const float* __restrict__ reg0, const float* __restrict__ reg1,
    const float* __restrict__ reg2, const float* __restrict__ reg3,
    const float* __restrict__ reg4,
    const float* __restrict__ loc0, const float* __restrict__ loc1,
    const float* __restrict__ loc2, const float* __restrict__ loc3,
    const float* __restrict__ loc4,
    float* __restrict__ out)
{
    const int hw_tab[5]   = {16384, 4096, 1024, 256, 64};
    const int k_tab[5]    = {1000, 1000, 1000, 256, 64};
    const float nf_tab[5] = {16.f, 32.f, 64.f, 128.f, 256.f};
    const int base_tab[5] = {0, 524288, 655360, 688128, 696320};

    int L = blockIdx.x >> 5;
    int n = blockIdx.x & 31;
    int hw = hw_tab[L];
    int kk = k_tab[L];
    float nf = nf_tab[L];
    int base = base_tab[L] + n * hw;

    const float* regp;
    const float* locp;
    switch (L) {
        case 0: regp = reg0; locp = loc0; break;
        case 1: regp = reg1; locp = loc1; break;
        case 2: regp = reg2; locp = loc2; break;
        case 3: regp = reg3; locp = loc3; break;
        default: regp = reg4; locp = loc4; break;
    }

    const uint32_t* sc = sc_all + base;
    const uint8_t* lab = lab_all + base;

    __shared__ uint32_t hist[256];
    __shared__ unsigned long long keys[1024];
    __shared__ int sh_cnt;
    __shared__ uint32_t sh_byte;
    __shared__ int sh_rem;
    __shared__ int sh_V;

    int tid = threadIdx.x;

    // ---- count valid ----
    if (tid == 0) sh_V = 0;
    __syncthreads();
    {
        int cnt = 0;
        for (int i = tid; i < hw; i += 256) cnt += (sc[i] != 0u);
        atomicAdd(&sh_V, cnt);
    }
    __syncthreads();
    int V = sh_V;
    int m = (kk < V) ? kk : V;

    if (m > 0) {
        // ---- 4-pass radix select: find m-th largest key T ----
        uint32_t prefix = 0, maskHi = 0;
        int rem = m;
        for (int p = 0; p < 4; ++p) {
            int shift = 24 - 8 * p;
            hist[tid] = 0;
            __syncthreads();
            for (int i = tid; i < hw; i += 256) {
                uint32_t v = sc[i];
                if ((v & maskHi) == prefix)
                    atomicAdd(&hist[(v >> shift) & 0xFFu], 1u);
            }
            __syncthreads();
            if (tid == 0) {
                uint32_t cum = 0;
                for (int b = 255; b >= 0; --b) {
                    uint32_t c = hist[b];
                    if (cum + c >= (uint32_t)rem) {
                        sh_byte = (uint32_t)b;
                        sh_rem = rem - (int)cum;
                        break;
                    }
                    cum += c;
                }
            }
            __syncthreads();
            prefix |= (sh_byte << shift);
            maskHi |= (0xFFu << shift);
            rem = sh_rem;
        }
        uint32_t T = prefix;

        // ---- compact: all > T, then == T up to m ----
        if (tid == 0) sh_cnt = 0;
        __syncthreads();
        for (int i = tid; i < hw; i += 256) {
            uint32_t v = sc[i];
            if (v > T) {
                int pos = atomicAdd(&sh_cnt, 1);
                keys[pos] = ((unsigned long long)v << 32) |
                            (unsigned long long)(0xFFFFu - (uint32_t)i);
            }
        }
        __syncthreads();
        for (int i = tid; i < hw; i += 256) {
            uint32_t v = sc[i];
            if (v == T) {
                int pos = atomicAdd(&sh_cnt, 1);
                if (pos < m)
                    keys[pos] = ((unsigned long long)v << 32) |
                                (unsigned long long)(0xFFFFu - (uint32_t)i);
            }
        }
        __syncthreads();
        for (int j = tid; j < 1024; j += 256)
            if (j >= m) keys[j] = 0ull;
        __syncthreads();

        // ---- bitonic sort 1024 keys, descending ----
        for (int k = 2; k <= 1024; k <<= 1) {
            for (int j = k >> 1; j > 0; j >>= 1) {
                for (int t = tid; t < 1024; t += 256) {
                    int ixj = t ^ j;
                    if (ixj > t) {
                        unsigned long long a = keys[t];
                        unsigned long long b = keys[ixj];
                        bool up = ((t & k) == 0);
                        if (up ? (a < b) : (a > b)) {
                            keys[t] = b;
                            keys[ixj] = a;
                        }
                    }
                }
                __syncthreads();
            }
        }
    }

    // ---- output: 1000 rows per segment (zeros beyond m) ----
    const size_t ROWS = (size_t)NIMG * NLEV * KMAX;   // 160000
    const size_t SCO = ROWS * 7;                       // det size
    const size_t LABo = SCO + ROWS;
    const size_t VALo = LABo + ROWS;

    for (int j = tid; j < KMAX; j += 256) {
        int row = L * KMAX + j;
        float d0 = 0, d1 = 0, d2 = 0, d3 = 0, d4 = 0, d5 = 0, d6 = 0;
        float s = 0, lb = 0, vd = 0;
        if (j < m) {
            unsigned long long key = keys[j];
            uint32_t v = (uint32_t)(key >> 32);
            int idx = 0xFFFF - (int)(key & 0xFFFFFFFFull);
            float score = __uint_as_float(v & 0x7FFFFFFFu);
            float x = locp[2 * idx];
            float y = locp[2 * idx + 1];
            float r[5];
            for (int q = 0; q < 5; ++q) {
                float rv = regp[(size_t)(n * 5 + q) * hw + idx];
                r[q] = rv * rv * rv * nf;
            }
            d0 = x; d1 = y;
            d2 = x - r[0]; d3 = y - r[1];
            d4 = x - r[2]; d5 = y - r[3];
            d6 = r[4];
            s = score;
            lb = (float)(lab[idx] + 1);
            vd = 1.0f;
        }
        size_t rbase = (size_t)n * NLEV * KMAX + row;
        float* dp = out + rbase * 7;
        dp[0] = d0; dp[1] = d1; dp[2] = d2; dp[3] = d3;
        dp[4] = d4; dp[5] = d5; dp[6] = d6;
        out[SCO + rbase] = s;
        out[LABo + rbase] = lb;
        out[VALo + rbase] = vd;
    }
}

extern "C" void kernel_launch(void* const* d_in, const int* in_sizes, int n_in,
                              void* d_out, int out_size, void* d_ws, size_t ws_size,
                              hipStream_t stream)
{
    const float* loc[5];
    const float* cls[5];
    const float* reg[5];
    const float* ctr[5];
    for (int l = 0; l < 5; ++l) {
        loc[l] = (const float*)d_in[4 * l + 0];
        cls[l] = (const float*)d_in[4 * l + 1];
        reg[l] = (const float*)d_in[4 * l + 2];
        ctr[l] = (const float*)d_in[4 * l + 3];
    }

    uint32_t* sc = (uint32_t*)d_ws;
    uint8_t* labp = (uint8_t*)(sc + 698368);

    const int hws[5] = {16384, 4096, 1024, 256, 64};
    const int shifts[5] = {14, 12, 10, 8, 6};
    const int bases[5] = {0, 524288, 655360, 688128, 696320};

    for (int l = 0; l < 5; ++l) {
        int total = NIMG * hws[l];
        int blocks = (total + 255) / 256;
        hipLaunchKernelGGL(score_kernel, dim3(blocks), dim3(256), 0, stream,
                           cls[l], ctr[l], sc + bases[l], labp + bases[l],
                           hws[l], shifts[l], total);
    }

    hipLaunchKernelGGL(select_kernel, dim3(160), dim3(256), 0, stream,
                       sc, labp,
                       reg[0], reg[1], reg[2], reg[3], reg[4],
                       loc[0], loc[1], loc[2], loc[3], loc[4],
                       (float*)d_out);
}

// Round 2
// 174.339 us; speedup vs baseline: 1.8662x; 1.8662x over previous
//
#include <hip/hip_runtime.h>
#include <stdint.h>

#define NIMG 32
#define NCLS 15
#define KMAX 1000
#define NLEV 5

__device__ __forceinline__ float sig64(float x) {
    double e = exp(-(double)x);
    return (float)(1.0 / (1.0 + e));
}

// ---------------- fused score kernel (all 5 levels, one launch) ----------------
// ranks in logit space (monotone), computes only 3 f64 sigmoids per position.
__global__ __launch_bounds__(256) void score_kernel(
    const float* __restrict__ c0, const float* __restrict__ c1,
    const float* __restrict__ c2, const float* __restrict__ c3,
    const float* __restrict__ c4,
    const float* __restrict__ t0, const float* __restrict__ t1,
    const float* __restrict__ t2, const float* __restrict__ t3,
    const float* __restrict__ t4,
    uint32_t* __restrict__ sc, uint8_t* __restrict__ lab)
{
    int g = blockIdx.x * 256 + threadIdx.x;   // grid sized exactly: 698368 total
    int shift, base;
    const float* cp; const float* tp;
    if (g < 524288)      { base = 0;      shift = 14; cp = c0; tp = t0; }
    else if (g < 655360) { base = 524288; shift = 12; cp = c1; tp = t1; }
    else if (g < 688128) { base = 655360; shift = 10; cp = c2; tp = t2; }
    else if (g < 696320) { base = 688128; shift = 8;  cp = c3; tp = t3; }
    else                 { base = 696320; shift = 6;  cp = c4; tp = t4; }
    int local = g - base;
    int hw = 1 << shift;
    int n = local >> shift;
    int i = local & (hw - 1);

    const float* col = cp + (size_t)n * NCLS * hw + i;
    float xs[NCLS];
    #pragma unroll
    for (int c = 0; c < NCLS; ++c) xs[c] = col[(size_t)c * hw];

    // top-2 logits, first-index-of-max semantics on x
    float b1 = xs[0], b2 = -1e30f; int i1 = 0;
    #pragma unroll
    for (int c = 1; c < NCLS; ++c) {
        float x = xs[c];
        if (x > b1) { b2 = b1; b1 = x; i1 = c; }
        else if (x > b2) b2 = x;
    }
    float p1 = sig64(b1);
    float p2 = sig64(b2);
    int bl = i1;
    if (p1 == p2) {
        // rare f32-sigmoid tie: reproduce jnp.argmax first-index over p exactly
        #pragma unroll
        for (int c = 0; c < NCLS; ++c) {
            if (sig64(xs[c]) == p1) { bl = c; break; }
        }
    }
    float cf = sig64(tp[local]);
    bool cand = (p1 * cf) > 0.2f;
    sc[g] = cand ? (__float_as_uint(p1) | 0x80000000u) : 0u;
    lab[g] = (uint8_t)bl;
}

// ---------------- select kernel ----------------
__device__ __forceinline__ unsigned long long shfl_xor_u64(unsigned long long x, int m) {
    uint32_t lo = (uint32_t)x, hi = (uint32_t)(x >> 32);
    lo = (uint32_t)__shfl_xor((int)lo, m);
    hi = (uint32_t)__shfl_xor((int)hi, m);
    return ((unsigned long long)hi << 32) | lo;
}

__global__ __launch_bounds__(1024) void select_kernel(
    const uint32_t* __restrict__ sc_all,
    const uint8_t* __restrict__ lab_all,
    const float* __restrict__ reg0, const float* __restrict__ reg1,
    const float* __restrict__ reg2, const float* __restrict__ reg3,
    const float* __restrict__ reg4,
    const float* __restrict__ loc0, const float* __restrict__ loc1,
    const float* __restrict__ loc2, const float* __restrict__ loc3,
    const float* __restrict__ loc4,
    float* __restrict__ out)
{
    const int hw_tab[5]   = {16384, 4096, 1024, 256, 64};
    const int k_tab[5]    = {1000, 1000, 1000, 256, 64};
    const float nf_tab[5] = {16.f, 32.f, 64.f, 128.f, 256.f};
    const int base_tab[5] = {0, 524288, 655360, 688128, 696320};

    int L = blockIdx.x >> 5;
    int n = blockIdx.x & 31;
    int hw = hw_tab[L];
    int kk = k_tab[L];
    float nf = nf_tab[L];
    int base = base_tab[L] + n * hw;

    const float* regp; const float* locp;
    switch (L) {
        case 0: regp = reg0; locp = loc0; break;
        case 1: regp = reg1; locp = loc1; break;
        case 2: regp = reg2; locp = loc2; break;
        case 3: regp = reg3; locp = loc3; break;
        default: regp = reg4; locp = loc4; break;
    }
    const uint32_t* sc = sc_all + base;
    const uint8_t* lab = lab_all + base;

    __shared__ unsigned long long keys[1024];   // 8 KB
    __shared__ uint32_t whist[16 * 256];        // 16 KB per-wave hist
    __shared__ uint32_t hist[256];              // 1 KB
    __shared__ int sh_V, sh_cnt, sh_rem;
    __shared__ uint32_t sh_byte;

    int tid = threadIdx.x;
    int lane = tid & 63;
    int wv = tid >> 6;
    unsigned long long lt = (1ull << lane) - 1ull;

    if (tid == 0) { sh_V = 0; sh_cnt = 0; }
    __syncthreads();

    int m = 0;
    unsigned long long r = 0;

    if (hw > 1024) {
        // ---------- radix select over global (L1/L2-cached) ----------
        uint32_t prefixv = 0, maskHi = 0;
        int rem = 0;
        const uint4* s4 = (const uint4*)sc;
        int nv4 = hw >> 2;
        for (int p = 0; p < 4; ++p) {
            int shift = 24 - 8 * p;
            for (int i = tid; i < 4096; i += 1024) whist[i] = 0;
            __syncthreads();
            for (int i = tid; i < nv4; i += 1024) {
                uint4 v = s4[i];
                uint32_t a0 = v.x, a1 = v.y, a2 = v.z, a3 = v.w;
                uint32_t* wh = &whist[wv << 8];
                if ((a0 & maskHi) == prefixv) atomicAdd(&wh[(a0 >> shift) & 255u], 1u);
                if ((a1 & maskHi) == prefixv) atomicAdd(&wh[(a1 >> shift) & 255u], 1u);
                if ((a2 & maskHi) == prefixv) atomicAdd(&wh[(a2 >> shift) & 255u], 1u);
                if ((a3 & maskHi) == prefixv) atomicAdd(&wh[(a3 >> shift) & 255u], 1u);
            }
            __syncthreads();
            if (tid < 256) {
                uint32_t s = 0;
                #pragma unroll
                for (int w = 0; w < 16; ++w) s += whist[(w << 8) + tid];
                hist[tid] = s;
            }
            __syncthreads();
            if (p == 0) {
                // valid keys all have sign bit -> top byte >= 0x80; byte-0 bin == zero keys
                int V = hw - (int)hist[0];
                m = (kk < V) ? kk : V;
                rem = m;
            }
            if (tid < 64) {
                int b0 = 255 - (tid << 2);
                uint32_t s = hist[b0] + hist[b0 - 1] + hist[b0 - 2] + hist[b0 - 3];
                uint32_t pre = s;
                #pragma unroll
                for (int o = 1; o < 64; o <<= 1) {
                    uint32_t t = (uint32_t)__shfl_up((int)pre, o);
                    if (lane >= o) pre += t;
                }
                uint32_t excl = pre - s;
                unsigned long long mb = __ballot(pre >= (uint32_t)rem);
                int first = __ffsll(mb) - 1;
                if (lane == first) {
                    uint32_t cum = excl, byte = 0; int nr = 0;
                    #pragma unroll
                    for (int q = 0; q < 4; ++q) {
                        int b = b0 - q;
                        uint32_t c = hist[b];
                        if (cum + c >= (uint32_t)rem) { byte = (uint32_t)b; nr = rem - (int)cum; break; }
                        cum += c;
                    }
                    sh_byte = byte; sh_rem = nr;
                }
            }
            __syncthreads();
            prefixv |= (sh_byte << shift);
            maskHi  |= (0xFFu << shift);
            rem = sh_rem;
        }
        uint32_t T = prefixv;

        // ---------- compact all v >= T (ties resolved by full-key sort) ----------
        for (int i = tid; i < nv4; i += 1024) {
            uint4 v = s4[i];
            uint32_t a[4] = {v.x, v.y, v.z, v.w};
            #pragma unroll
            for (int c = 0; c < 4; ++c) {
                bool pr = (a[c] >= T) && (m > 0);
                unsigned long long mask = __ballot(pr);
                if (mask) {
                    int ldr = __ffsll(mask) - 1;
                    int bp = 0;
                    if (lane == ldr) bp = atomicAdd(&sh_cnt, __popcll(mask));
                    bp = __shfl(bp, ldr);
                    if (pr) {
                        int pos = bp + __popcll(mask & lt);
                        int idx = 4 * i + c;
                        if (pos < 1024)
                            keys[pos] = ((unsigned long long)a[c] << 32) |
                                        (unsigned long long)(0xFFFFu - (uint32_t)idx);
                    }
                }
            }
        }
        __syncthreads();
        int cnt = sh_cnt < 1024 ? sh_cnt : 1024;
        r = (tid < cnt) ? keys[tid] : 0ull;
    } else {
        // ---------- small levels: sort everything directly ----------
        uint32_t v = 0;
        if (tid < hw) v = sc[tid];
        unsigned long long mk = __ballot(v != 0u);
        if (lane == 0) atomicAdd(&sh_V, __popcll(mk));
        __syncthreads();
        int V = sh_V;
        m = (kk < V) ? kk : V;
        if (v != 0u)
            r = ((unsigned long long)v << 32) |
                (unsigned long long)(0xFFFFu - (uint32_t)tid);
    }

    // ---------- bitonic sort 1024 keys descending, register-resident ----------
    for (int k = 2; k <= 1024; k <<= 1) {
        for (int j = k >> 1; j > 0; j >>= 1) {
            unsigned long long o;
            if (j >= 64) {
                __syncthreads();
                keys[tid] = r;
                __syncthreads();
                o = keys[tid ^ j];
            } else {
                o = shfl_xor_u64(r, j);
            }
            bool keepMax = ((tid & k) == 0) ^ ((tid & j) != 0);
            bool take = keepMax ? (o > r) : (o < r);
            if (take) r = o;
        }
    }

    // ---------- output ----------
    const size_t ROWS = (size_t)NIMG * NLEV * KMAX;
    const size_t SCO = ROWS * 7;
    const size_t LABo = SCO + ROWS;
    const size_t VALo = LABo + ROWS;

    int j = tid;
    if (j < KMAX) {
        float d0=0,d1=0,d2=0,d3=0,d4=0,d5=0,d6=0,s=0,lb=0,vd=0;
        if (j < m) {
            uint32_t v = (uint32_t)(r >> 32);
            int idx = 0xFFFF - (int)(r & 0xFFFFFFFFull);
            float score = __uint_as_float(v & 0x7FFFFFFFu);
            float x = locp[2 * idx];
            float y = locp[2 * idx + 1];
            float rr[5];
            #pragma unroll
            for (int q = 0; q < 5; ++q) {
                float rv = regp[(size_t)(n * 5 + q) * hw + idx];
                rr[q] = rv * rv * rv * nf;
            }
            d0 = x; d1 = y;
            d2 = x - rr[0]; d3 = y - rr[1];
            d4 = x - rr[2]; d5 = y - rr[3];
            d6 = rr[4];
            s = score;
            lb = (float)(lab[idx] + 1);
            vd = 1.0f;
        }
        size_t rbase = (size_t)n * (NLEV * KMAX) + L * KMAX + j;
        float* dp = out + rbase * 7;
        dp[0]=d0; dp[1]=d1; dp[2]=d2; dp[3]=d3; dp[4]=d4; dp[5]=d5; dp[6]=d6;
        out[SCO + rbase] = s;
        out[LABo + rbase] = lb;
        out[VALo + rbase] = vd;
    }
}

extern "C" void kernel_launch(void* const* d_in, const int* in_sizes, int n_in,
                              void* d_out, int out_size, void* d_ws, size_t ws_size,
                              hipStream_t stream)
{
    const float* loc[5]; const float* cls[5]; const float* reg[5]; const float* ctr[5];
    for (int l = 0; l < 5; ++l) {
        loc[l] = (const float*)d_in[4 * l + 0];
        cls[l] = (const float*)d_in[4 * l + 1];
        reg[l] = (const float*)d_in[4 * l + 2];
        ctr[l] = (const float*)d_in[4 * l + 3];
    }
    uint32_t* sc = (uint32_t*)d_ws;
    uint8_t* labp = (uint8_t*)(sc + 698368);

    hipLaunchKernelGGL(score_kernel, dim3(2728), dim3(256), 0, stream,
                       cls[0], cls[1], cls[2], cls[3], cls[4],
                       ctr[0], ctr[1], ctr[2], ctr[3], ctr[4],
                       sc, labp);

    hipLaunchKernelGGL(select_kernel, dim3(160), dim3(1024), 0, stream,
                       sc, labp,
                       reg[0], reg[1], reg[2], reg[3], reg[4],
                       loc[0], loc[1], loc[2], loc[3], loc[4],
                       (float*)d_out);
}

// Round 3
// 172.585 us; speedup vs baseline: 1.8852x; 1.0102x over previous
//
#include <hip/hip_runtime.h>
#include <stdint.h>

#define NIMG 32
#define NCLS 15
#define KMAX 1000
#define NLEV 5

__device__ __forceinline__ float sig64(float x) {
    double e = exp(-(double)x);
    return (float)(1.0 / (1.0 + e));
}

// ---------------- fused score kernel: 4 positions/thread, float4 streams ----
__global__ __launch_bounds__(256) void score_kernel(
    const float* __restrict__ c0, const float* __restrict__ c1,
    const float* __restrict__ c2, const float* __restrict__ c3,
    const float* __restrict__ c4,
    const float* __restrict__ t0, const float* __restrict__ t1,
    const float* __restrict__ t2, const float* __restrict__ t3,
    const float* __restrict__ t4,
    uint32_t* __restrict__ sc, uint8_t* __restrict__ lab)
{
    int g4 = blockIdx.x * 256 + threadIdx.x;    // 174592 groups exactly
    int p = g4 << 2;
    int shift, base;
    const float* cp; const float* tp;
    if (p < 524288)      { base = 0;      shift = 14; cp = c0; tp = t0; }
    else if (p < 655360) { base = 524288; shift = 12; cp = c1; tp = t1; }
    else if (p < 688128) { base = 655360; shift = 10; cp = c2; tp = t2; }
    else if (p < 696320) { base = 688128; shift = 8;  cp = c3; tp = t3; }
    else                 { base = 696320; shift = 6;  cp = c4; tp = t4; }
    int local = p - base;
    int hw = 1 << shift;
    int n = local >> shift;
    int i = local & (hw - 1);

    const float* col = cp + (size_t)n * NCLS * hw + i;

    float4 b1 = *(const float4*)col;
    float4 b2 = make_float4(-1e30f, -1e30f, -1e30f, -1e30f);
    int4 i1 = make_int4(0, 0, 0, 0);

#define UPD(xv, b1v, b2v, i1v, cc) \
    if ((xv) > (b1v)) { (b2v) = (b1v); (b1v) = (xv); (i1v) = (cc); } \
    else if ((xv) > (b2v)) (b2v) = (xv);

    #pragma unroll
    for (int c = 1; c < NCLS; ++c) {
        float4 x = *(const float4*)(col + (size_t)c * hw);
        UPD(x.x, b1.x, b2.x, i1.x, c)
        UPD(x.y, b1.y, b2.y, i1.y, c)
        UPD(x.z, b1.z, b2.z, i1.z, c)
        UPD(x.w, b1.w, b2.w, i1.w, c)
    }
#undef UPD

    float4 ct = *(const float4*)(tp + local);

    uint32_t ow[4];
    uint32_t ol[4];
    float b1a[4] = {b1.x, b1.y, b1.z, b1.w};
    float b2a[4] = {b2.x, b2.y, b2.z, b2.w};
    int   i1a[4] = {i1.x, i1.y, i1.z, i1.w};
    float cta[4] = {ct.x, ct.y, ct.z, ct.w};

    #pragma unroll
    for (int q = 0; q < 4; ++q) {
        float p1 = sig64(b1a[q]);
        float p2 = sig64(b2a[q]);
        int bl = i1a[q];
        if (p1 == p2) {
            // rare f32-sigmoid tie: first-index-of-max over sigmoid, exact
            for (int c = 0; c < NCLS; ++c) {
                if (sig64(col[(size_t)c * hw + q]) == p1) { bl = c; break; }
            }
        }
        float cf = sig64(cta[q]);
        bool cand = (p1 * cf) > 0.2f;
        ow[q] = cand ? (__float_as_uint(p1) | 0x80000000u) : 0u;
        ol[q] = (uint32_t)bl;
    }

    *(uint4*)(sc + p) = make_uint4(ow[0], ow[1], ow[2], ow[3]);
    *(uint32_t*)(lab + p) = ol[0] | (ol[1] << 8) | (ol[2] << 16) | (ol[3] << 24);
}

// ---------------- select kernel ----------------
__device__ __forceinline__ unsigned long long shfl_xor_u64(unsigned long long x, int m) {
    uint32_t lo = (uint32_t)x, hi = (uint32_t)(x >> 32);
    lo = (uint32_t)__shfl_xor((int)lo, m);
    hi = (uint32_t)__shfl_xor((int)hi, m);
    return ((unsigned long long)hi << 32) | lo;
}

__global__ __launch_bounds__(1024) void select_kernel(
    const uint32_t* __restrict__ sc_all,
    const uint8_t* __restrict__ lab_all,
    const float* __restrict__ reg0, const float* __restrict__ reg1,
    const float* __restrict__ reg2, const float* __restrict__ reg3,
    const float* __restrict__ reg4,
    const float* __restrict__ loc0, const float* __restrict__ loc1,
    const float* __restrict__ loc2, const float* __restrict__ loc3,
    const float* __restrict__ loc4,
    float* __restrict__ out)
{
    const int hw_tab[5]   = {16384, 4096, 1024, 256, 64};
    const int k_tab[5]    = {1000, 1000, 1000, 256, 64};
    const float nf_tab[5] = {16.f, 32.f, 64.f, 128.f, 256.f};
    const int base_tab[5] = {0, 524288, 655360, 688128, 696320};

    int L = blockIdx.x >> 5;
    int n = blockIdx.x & 31;
    int hw = hw_tab[L];
    int kk = k_tab[L];
    float nf = nf_tab[L];
    int base = base_tab[L] + n * hw;

    const float* regp; const float* locp;
    switch (L) {
        case 0: regp = reg0; locp = loc0; break;
        case 1: regp = reg1; locp = loc1; break;
        case 2: regp = reg2; locp = loc2; break;
        case 3: regp = reg3; locp = loc3; break;
        default: regp = reg4; locp = loc4; break;
    }
    const uint32_t* sc = sc_all + base;
    const uint8_t* lab = lab_all + base;

    __shared__ unsigned long long keys[2048];   // 16 KB
    __shared__ uint32_t hist[1024];             // 4 KB
    __shared__ uint32_t wsum[16];
    __shared__ int sh_cnt, sh_m, sh_B, sh_V;

    int tid = threadIdx.x;
    int lane = tid & 63;
    int wv = tid >> 6;
    unsigned long long lt = (1ull << lane) - 1ull;
    int i0 = tid, i1idx = tid + 1024;

    hist[tid] = 0;
    if (tid == 0) { sh_cnt = 0; sh_V = 0; }
    __syncthreads();

    int m = 0;
    unsigned long long r0 = 0, r1 = 0;

    if (hw > 1024) {
        // ---- pass 1: histogram of key bits[24:15] (monotone in score) ----
        // all valid keys have bits[31:25] == 0x5F (score in (0.2, 1.0])
        const uint4* s4 = (const uint4*)sc;
        int nv4 = hw >> 2;
        for (int i = tid; i < nv4; i += 1024) {
            uint4 v = s4[i];
            if (v.x) atomicAdd(&hist[(v.x >> 15) & 0x3FFu], 1u);
            if (v.y) atomicAdd(&hist[(v.y >> 15) & 0x3FFu], 1u);
            if (v.z) atomicAdd(&hist[(v.z >> 15) & 0x3FFu], 1u);
            if (v.w) atomicAdd(&hist[(v.w >> 15) & 0x3FFu], 1u);
        }
        __syncthreads();

        // ---- suffix scan: x = count(bins >= b), b = 1023 - tid ----
        uint32_t h = hist[1023 - tid];
        uint32_t x = h;
        #pragma unroll
        for (int o = 1; o < 64; o <<= 1) {
            uint32_t t = (uint32_t)__shfl_up((int)x, o);
            if (lane >= o) x += t;
        }
        if (lane == 63) wsum[wv] = x;
        __syncthreads();
        uint32_t off = 0;
        for (int w = 0; w < wv; ++w) off += wsum[w];
        x += off;
        int b = 1023 - tid;
        if (tid == 1023) sh_m = (kk < (int)x) ? kk : (int)x;   // V = suffix(0)
        __syncthreads();
        m = sh_m;
        if (m > 0) {
            // unique crossing: suffix(b) >= m and suffix(b+1) < m
            if (x >= (uint32_t)m && (x - h) < (uint32_t)m) sh_B = b;
            __syncthreads();
            uint32_t T = 0xBE000000u | ((uint32_t)sh_B << 15);

            // ---- pass 2: compact all keys >= T (capacity 2048) ----
            for (int i = tid; i < nv4; i += 1024) {
                uint4 v = s4[i];
                uint32_t a[4] = {v.x, v.y, v.z, v.w};
                #pragma unroll
                for (int c = 0; c < 4; ++c) {
                    bool pr = (a[c] >= T);
                    unsigned long long mask = __ballot(pr);
                    if (mask) {
                        int ldr = __ffsll((long long)mask) - 1;
                        int bp = 0;
                        if (lane == ldr) bp = atomicAdd(&sh_cnt, __popcll(mask));
                        bp = __shfl(bp, ldr);
                        if (pr) {
                            int pos = bp + __popcll(mask & lt);
                            int idx = 4 * i + c;
                            if (pos < 2048)
                                keys[pos] = ((unsigned long long)a[c] << 32) |
                                            (unsigned long long)(0xFFFFu - (uint32_t)idx);
                        }
                    }
                }
            }
            __syncthreads();
            int cnt = sh_cnt < 2048 ? sh_cnt : 2048;
            r0 = (tid < cnt) ? keys[tid] : 0ull;
            r1 = (tid + 1024 < cnt) ? keys[tid + 1024] : 0ull;
        }
    } else {
        // ---- small levels: take everything, sort directly ----
        uint32_t v = (tid < hw) ? sc[tid] : 0u;
        unsigned long long mk = __ballot(v != 0u);
        if (lane == 0) atomicAdd(&sh_V, __popcll(mk));
        __syncthreads();
        int V = sh_V;
        m = (kk < V) ? kk : V;
        if (v != 0u)
            r0 = ((unsigned long long)v << 32) |
                 (unsigned long long)(0xFFFFu - (uint32_t)tid);
    }

    // ---- bitonic sort 2048 keys descending, 2 regs/thread ----
    for (int k = 2; k <= 2048; k <<= 1) {
        for (int j = k >> 1; j > 0; j >>= 1) {
            if (j >= 1024) {
                // partner is the other register of the same thread
                unsigned long long hi = (r0 > r1) ? r0 : r1;
                unsigned long long lo = (r0 > r1) ? r1 : r0;
                r0 = hi; r1 = lo;     // keepMax(i0)=true, keepMax(i1)=false at k=2048
            } else if (j >= 64) {
                __syncthreads();
                keys[tid] = r0;
                keys[tid + 1024] = r1;
                __syncthreads();
                unsigned long long o0 = keys[i0 ^ j];
                unsigned long long o1 = keys[i1idx ^ j];
                bool km0 = ((i0 & k) == 0) ^ ((i0 & j) != 0);
                bool km1 = ((i1idx & k) == 0) ^ ((i1idx & j) != 0);
                r0 = km0 ? (o0 > r0 ? o0 : r0) : (o0 < r0 ? o0 : r0);
                r1 = km1 ? (o1 > r1 ? o1 : r1) : (o1 < r1 ? o1 : r1);
            } else {
                unsigned long long o0 = shfl_xor_u64(r0, j);
                unsigned long long o1 = shfl_xor_u64(r1, j);
                bool km0 = ((i0 & k) == 0) ^ ((i0 & j) != 0);
                bool km1 = ((i1idx & k) == 0) ^ ((i1idx & j) != 0);
                r0 = km0 ? (o0 > r0 ? o0 : r0) : (o0 < r0 ? o0 : r0);
                r1 = km1 ? (o1 > r1 ? o1 : r1) : (o1 < r1 ? o1 : r1);
            }
        }
    }

    // ---- output: elements 0..1023 live in r0 of threads 0..1023 ----
    const size_t ROWS = (size_t)NIMG * NLEV * KMAX;
    const size_t SCO = ROWS * 7;
    const size_t LABo = SCO + ROWS;
    const size_t VALo = LABo + ROWS;

    if (tid < KMAX) {
        float d0=0,d1=0,d2=0,d3=0,d4=0,d5=0,d6=0,s=0,lb=0,vd=0;
        if (tid < m) {
            uint32_t v = (uint32_t)(r0 >> 32);
            int idx = 0xFFFF - (int)(r0 & 0xFFFFFFFFull);
            float score = __uint_as_float(v & 0x7FFFFFFFu);
            float x = locp[2 * idx];
            float y = locp[2 * idx + 1];
            float rr[5];
            #pragma unroll
            for (int q = 0; q < 5; ++q) {
                float rv = regp[(size_t)(n * 5 + q) * hw + idx];
                rr[q] = rv * rv * rv * nf;
            }
            d0 = x; d1 = y;
            d2 = x - rr[0]; d3 = y - rr[1];
            d4 = x - rr[2]; d5 = y - rr[3];
            d6 = rr[4];
            s = score;
            lb = (float)(lab[idx] + 1);
            vd = 1.0f;
        }
        size_t rbase = (size_t)n * (NLEV * KMAX) + L * KMAX + tid;
        float* dp = out + rbase * 7;
        dp[0]=d0; dp[1]=d1; dp[2]=d2; dp[3]=d3; dp[4]=d4; dp[5]=d5; dp[6]=d6;
        out[SCO + rbase] = s;
        out[LABo + rbase] = lb;
        out[VALo + rbase] = vd;
    }
}

extern "C" void kernel_launch(void* const* d_in, const int* in_sizes, int n_in,
                              void* d_out, int out_size, void* d_ws, size_t ws_size,
                              hipStream_t stream)
{
    const float* loc[5]; const float* cls[5]; const float* reg[5]; const float* ctr[5];
    for (int l = 0; l < 5; ++l) {
        loc[l] = (const float*)d_in[4 * l + 0];
        cls[l] = (const float*)d_in[4 * l + 1];
        reg[l] = (const float*)d_in[4 * l + 2];
        ctr[l] = (const float*)d_in[4 * l + 3];
    }
    uint32_t* sc = (uint32_t*)d_ws;
    uint8_t* labp = (uint8_t*)(sc + 698368);

    hipLaunchKernelGGL(score_kernel, dim3(682), dim3(256), 0, stream,
                       cls[0], cls[1], cls[2], cls[3], cls[4],
                       ctr[0], ctr[1], ctr[2], ctr[3], ctr[4],
                       sc, labp);

    hipLaunchKernelGGL(select_kernel, dim3(160), dim3(1024), 0, stream,
                       sc, labp,
                       reg[0], reg[1], reg[2], reg[3], reg[4],
                       loc[0], loc[1], loc[2], loc[3], loc[4],
                       (float*)d_out);
}